// Round 5
// baseline (164.705 us; speedup 1.0000x reference)
//
#include <hip/hip_runtime.h>
#include <math.h>

#define BLOCK 256
#define PPT 4                    // poses per thread: 144B rot group = 9 aligned float4
#define TILE (BLOCK * PPT)       // 1024 poses per block-iteration
#define GROUP_WORDS 52           // 4 goal poses (48 words) padded to 52 words = 208B:
                                 // 16B-aligned for b128, lane word-stride 52 -> free 2-way banks

typedef unsigned int u32;

__device__ __forceinline__ void pose_cost(const float* __restrict__ R,
                                          const float* __restrict__ P,
                                          const float* __restrict__ G,
                                          const float* __restrict__ GP,
                                          float& cost, float& rotn, float& gd)
{
  // t[i] = -sum_j G[j,i]*GP[j] + sum_j R[j,i]*P[j]
  float t0 = 0.f, t1 = 0.f, t2 = 0.f;
  #pragma unroll
  for (int j = 0; j < 3; ++j) {
    t0 += R[j*3+0]*P[j] - G[j*3+0]*GP[j];
    t1 += R[j*3+1]*P[j] - G[j*3+1]*GP[j];
    t2 += R[j*3+2]*P[j] - G[j*3+2]*GP[j];
  }
  const float pos_err = t0*t0 + t1*t1 + t2*t2;
  gd = __builtin_amdgcn_sqrtf(pos_err);                      // arg >= 0

  // ee_R_g[i,j] = sum_k G[k,i]*R[k,j]; d = I - ee_R_g
  float rn[3];
  #pragma unroll
  for (int i = 0; i < 3; ++i) {
    float q = 0.f;
    #pragma unroll
    for (int j = 0; j < 3; ++j) {
      float m = G[0+i]*R[0+j] + G[3+i]*R[3+j] + G[6+i]*R[6+j];
      float d = (i == j ? 1.f : 0.f) - m;
      q += d*d;
    }
    rn[i] = __builtin_amdgcn_sqrtf(q);
  }
  const float ssum = rn[0] + rn[1] + rn[2];
  rotn = __builtin_amdgcn_sqrtf(rn[0]*rn[0] + rn[1]*rn[1] + rn[2]*rn[2]);
  // rot_err = ssum^2 hinged on gd <= 100; sqrt(ssum^2) == ssum (ssum >= 0);
  // convergence thresholds are 0 -> no-op on non-negative values.
  cost = (gd <= 100.0f ? ssum : 0.f) + gd;
}

// Fast path: H % 4 == 0, goal table fits LDS. One barrier total; then a pure
// grid-stride loop with 12 float4 loads + 3 float4 stores per 4 poses.
__global__ __launch_bounds__(BLOCK, 4) void traj_cost_fast(
    const float* __restrict__ pos,    // (N, 3)
    const float* __restrict__ rot,    // (N, 3, 3)
    const float* __restrict__ gpos,   // (H, 3)
    const float* __restrict__ grot,   // (H, 3, 3)
    float* __restrict__ out,          // cost[N] | rot_err_norm[N] | goal_dist[N]
    long long N, int H)
{
  extern __shared__ float sg[];       // (H/4) * GROUP_WORDS words
  const int tid = threadIdx.x;

  // ---- goal staging, grouped-by-4, once per block ----
  // group g holds rows 4g..4g+3; pose j at word offset j*12 (9 rot + 3 pos).
  const u32 uH = (u32)H;
  for (u32 e = tid; e < 12u * uH; e += BLOCK) {
    const u32 r = e / 12u, c = e % 12u;
    const float v = (c < 9u) ? grot[r * 9u + c] : gpos[r * 3u + (c - 9u)];
    sg[(r >> 2) * GROUP_WORDS + (r & 3u) * 12u + c] = v;
  }
  __syncthreads();                    // the only barrier in the kernel

  const long long step = (long long)gridDim.x * TILE;
  const u32 stepH = (u32)(step % (long long)H);
  u32 h0 = (u32)(((long long)blockIdx.x * TILE) % (long long)H);  // block-uniform

  for (long long base = (long long)blockIdx.x * TILE; base < N;
       base += step, h0 = (h0 + stepH >= uH ? h0 + stepH - uH : h0 + stepH)) {
    const long long idx = base + (long long)(PPT * tid);
    if (idx >= N) continue;

    // h for this thread's 4 poses: h..h+3, h % 4 == 0 (TILE,H multiples of 4)
    // -> exactly one goal group, no wrap inside the group.
    u32 h = h0 + 4u * (u32)tid;
    h %= uH;
    const float* gr = sg + (h >> 2) * GROUP_WORDS;

    if (idx + PPT <= N) {
      // 12 aligned float4 loads: idx%4==0 -> byte offsets idx*36 / idx*12 are 16B-aligned.
      float4 rv[9], pv[3];
      const float4* r4 = (const float4*)(rot + idx * 9);
      #pragma unroll
      for (int k = 0; k < 9; ++k) rv[k] = r4[k];
      const float4* p4 = (const float4*)(pos + idx * 3);
      #pragma unroll
      for (int k = 0; k < 3; ++k) pv[k] = p4[k];
      const float* Rf = (const float*)rv;
      const float* Pf = (const float*)pv;

      float oc[4], on[4], og[4];
      #pragma unroll
      for (int j = 0; j < 4; ++j) {
        float Gj[12];
        const float4* g4 = (const float4*)(gr + j * 12);   // 48B per pose, 16B-aligned
        *(float4*)(Gj)     = g4[0];
        *(float4*)(Gj + 4) = g4[1];
        *(float4*)(Gj + 8) = g4[2];
        pose_cost(Rf + 9 * j, Pf + 3 * j, Gj, Gj + 9, oc[j], on[j], og[j]);
      }
      // N % 4 == 0 not required for these stores: idx+PPT<=N and idx%4==0,
      // but out+N+idx needs N%4==0 for 16B alignment -> host guarantees or
      // falls back. (Checked in kernel_launch.)
      *(float4*)(out + idx)         = *(float4*)oc;
      *(float4*)(out + N + idx)     = *(float4*)on;
      *(float4*)(out + 2 * N + idx) = *(float4*)og;
    } else {
      // tail group: scalar per pose
      for (int j = 0; j < PPT && idx + j < N; ++j) {
        float R[9], P[3];
        #pragma unroll
        for (int c = 0; c < 9; ++c) R[c] = rot[(idx + j) * 9 + c];
        #pragma unroll
        for (int c = 0; c < 3; ++c) P[c] = pos[(idx + j) * 3 + c];
        const float* Gj = gr + j * 12;
        float c0, c1, c2;
        pose_cost(R, P, Gj, Gj + 9, c0, c1, c2);
        out[idx + j]         = c0;
        out[N + idx + j]     = c1;
        out[2 * N + idx + j] = c2;
      }
    }
  }
}

// Generic fallback: one pose per thread, direct global goal reads.
__global__ __launch_bounds__(BLOCK) void traj_cost_generic(
    const float* __restrict__ pos, const float* __restrict__ rot,
    const float* __restrict__ gpos, const float* __restrict__ grot,
    float* __restrict__ out, long long N, int H)
{
  const long long stride = (long long)gridDim.x * BLOCK;
  for (long long idx = (long long)blockIdx.x * BLOCK + threadIdx.x; idx < N;
       idx += stride) {
    const int h = (int)(idx % (long long)H);
    float R[9], P[3], G[12];
    #pragma unroll
    for (int c = 0; c < 9; ++c) R[c] = rot[idx * 9 + c];
    #pragma unroll
    for (int c = 0; c < 3; ++c) P[c] = pos[idx * 3 + c];
    #pragma unroll
    for (int c = 0; c < 9; ++c) G[c] = grot[(size_t)h * 9 + c];
    #pragma unroll
    for (int c = 0; c < 3; ++c) G[9 + c] = gpos[(size_t)h * 3 + c];
    float c0, c1, c2;
    pose_cost(R, P, G, G + 9, c0, c1, c2);
    out[idx]         = c0;
    out[N + idx]     = c1;
    out[2 * N + idx] = c2;
  }
}

extern "C" void kernel_launch(void* const* d_in, const int* in_sizes, int n_in,
                              void* d_out, int out_size, void* d_ws, size_t ws_size,
                              hipStream_t stream) {
  const float* pos  = (const float*)d_in[0];
  const float* rot  = (const float*)d_in[1];
  const float* gpos = (const float*)d_in[2];
  const float* grot = (const float*)d_in[3];
  float* out = (float*)d_out;

  const long long N = (long long)in_sizes[0] / 3;   // B*H poses
  const int H = in_sizes[2] / 3;

  const size_t goal_lds = (size_t)((H + 3) / 4) * GROUP_WORDS * sizeof(float);
  const bool fast = (H % 4 == 0) && (N % 4 == 0) && goal_lds <= 48 * 1024;

  if (fast) {
    const long long ntiles = (N + TILE - 1) / TILE;
    const int blocks = (int)(ntiles < 1024 ? ntiles : 1024);  // 4 blk/CU, 16 waves/CU
    traj_cost_fast<<<blocks, BLOCK, goal_lds, stream>>>(pos, rot, gpos, grot,
                                                        out, N, H);
  } else {
    const long long nb = (N + BLOCK - 1) / BLOCK;
    const int blocks = (int)(nb < 2048 ? nb : 2048);
    traj_cost_generic<<<blocks, BLOCK, 0, stream>>>(pos, rot, gpos, grot,
                                                    out, N, H);
  }
}

// Round 6
// 142.051 us; speedup vs baseline: 1.1595x; 1.1595x over previous
//
#include <hip/hip_runtime.h>
#include <math.h>

#define BLOCK 256
#define GRP 64                      // poses per wave-group
#define ROT_W 576                   // slab rot region words (64*9)
#define POS_W 192                   // slab pos region words (64*3)
#define SLAB_W (ROT_W + POS_W)      // 768 words = 3 KB
#define WAVE_W (2 * SLAB_W)         // double slab per wave

typedef unsigned int u32;

__device__ __forceinline__ void dma16(float* lds, const float* g) {
  // async global->LDS: wave-uniform LDS base, HW adds lane*16; per-lane global src.
  __builtin_amdgcn_global_load_lds(
      (const __attribute__((address_space(1))) u32*)g,
      (__attribute__((address_space(3))) u32*)lds, 16, 0, 0);
}

__device__ __forceinline__ void pose_cost(const float* __restrict__ R,
                                          const float* __restrict__ P,
                                          const float* __restrict__ G,
                                          const float* __restrict__ GP,
                                          float& cost, float& rotn, float& gd)
{
  // t[i] = -sum_j G[j,i]*GP[j] + sum_j R[j,i]*P[j]
  float t0 = 0.f, t1 = 0.f, t2 = 0.f;
  #pragma unroll
  for (int j = 0; j < 3; ++j) {
    t0 += R[j*3+0]*P[j] - G[j*3+0]*GP[j];
    t1 += R[j*3+1]*P[j] - G[j*3+1]*GP[j];
    t2 += R[j*3+2]*P[j] - G[j*3+2]*GP[j];
  }
  const float pos_err = t0*t0 + t1*t1 + t2*t2;
  gd = __builtin_amdgcn_sqrtf(pos_err);                      // arg >= 0

  // ee_R_g[i,j] = sum_k G[k,i]*R[k,j]; d = I - ee_R_g
  float rn[3];
  #pragma unroll
  for (int i = 0; i < 3; ++i) {
    float q = 0.f;
    #pragma unroll
    for (int j = 0; j < 3; ++j) {
      float m = G[0+i]*R[0+j] + G[3+i]*R[3+j] + G[6+i]*R[6+j];
      float d = (i == j ? 1.f : 0.f) - m;
      q += d*d;
    }
    rn[i] = __builtin_amdgcn_sqrtf(q);
  }
  const float ssum = rn[0] + rn[1] + rn[2];
  rotn = __builtin_amdgcn_sqrtf(rn[0]*rn[0] + rn[1]*rn[1] + rn[2]*rn[2]);
  // rot_err = ssum^2 hinged on gd <= 100; sqrt(ssum^2)==ssum (ssum>=0);
  // convergence thresholds are 0 -> no-op on non-negative values.
  cost = (gd <= 100.0f ? ssum : 0.f) + gd;
}

// Fast path: N % 64 == 0, H % 64 == 0, goal table fits LDS.
// Wave-autonomous streaming: per 64-pose group, 4 DMA chunks into a
// wave-private double slab; counted vmcnt sync; NO per-iteration barrier.
__global__ __launch_bounds__(BLOCK, 4) void traj_cost_wave(
    const float* __restrict__ pos,    // (N, 3)
    const float* __restrict__ rot,    // (N, 3, 3)
    const float* __restrict__ gpos,   // (H, 3)
    const float* __restrict__ grot,   // (H, 3, 3)
    float* __restrict__ out,          // cost[N] | rot_err_norm[N] | goal_dist[N]
    long long N, int H)
{
  extern __shared__ float smem[];     // [4 waves x 2 slabs][goal table 12*H]
  const int tid  = threadIdx.x;
  const int wv   = tid >> 6;
  const int lane = tid & 63;
  float* slab = smem + wv * WAVE_W;   // [rotA 576 | posA 192 | rotB 576 | posB 192]
  float* sg   = smem + 4 * WAVE_W;    // goal records: 12 words = [9 rot | 3 pos]

  // ---- goal staging (once per block) + the ONLY barrier in the kernel ----
  const u32 uH = (u32)H;
  for (u32 k = tid; k < 12u * uH; k += BLOCK) {
    const u32 r = k / 12u, c = k % 12u;
    sg[k] = (c < 9u) ? grot[r * 9u + c] : gpos[r * 3u + (c - 9u)];
  }
  __syncthreads();

  const u32 nGroups = (u32)(N / GRP);
  const u32 wid     = (u32)blockIdx.x * (BLOCK / 64) + (u32)wv;
  const u32 wstride = (u32)gridDim.x * (BLOCK / 64);
  if (wid >= nGroups) return;

  u32 g  = wid;
  u32 h0 = (u32)(((unsigned long long)g * GRP) % uH);          // multiple of 64
  const u32 hstep = (u32)(((unsigned long long)wstride * GRP) % uH);

  // ---- prologue: DMA group g into slab half 0 ----
  {
    const float* rs = rot + (size_t)g * GRP * 9;   // 2304 B, 16B-aligned
    const float* ps = pos + (size_t)g * GRP * 3;   // 768 B, 16B-aligned
    dma16(slab,        rs + lane * 4);
    dma16(slab + 256,  rs + 256 + lane * 4);
    if (lane < 16) dma16(slab + 512, rs + 512 + lane * 4);
    if (lane < 48) dma16(slab + ROT_W, ps + lane * 4);
  }

  int cur = 0;
  bool first = true;
  for (;;) {
    const u32 gn = g + wstride;
    const bool has_next = (gn < nGroups);

    // Issue next group's 4 DMAs BEFORE waiting: they ride out the compute
    // phase (counted vmcnt leaves them in flight — T4 pattern).
    if (has_next) {
      float* nb = slab + (cur ^ 1) * SLAB_W;
      const float* rs = rot + (size_t)gn * GRP * 9;
      const float* ps = pos + (size_t)gn * GRP * 3;
      dma16(nb,        rs + lane * 4);
      dma16(nb + 256,  rs + 256 + lane * 4);
      if (lane < 16) dma16(nb + 512, rs + 512 + lane * 4);
      if (lane < 48) dma16(nb + ROT_W, ps + lane * 4);
    }

    // Wait for CURRENT slab's DMAs only. Outstanding newer ops:
    //   steady state: 3 stores (prev iter) + 4 next-DMAs = 7
    //   first iter:   4 next-DMAs                         = 4
    //   last iter:    3 stores                            = 3
    //   single iter:  0
    if (has_next) {
      if (first) asm volatile("s_waitcnt vmcnt(4)" ::: "memory");
      else       asm volatile("s_waitcnt vmcnt(7)" ::: "memory");
    } else {
      if (first) asm volatile("s_waitcnt vmcnt(0)" ::: "memory");
      else       asm volatile("s_waitcnt vmcnt(3)" ::: "memory");
    }
    __builtin_amdgcn_sched_barrier(0);   // keep slab ds_reads below the wait

    // ---- compute current group ----
    const float* rsl = slab + cur * SLAB_W;
    const float* psl = rsl + ROT_W;
    float R[9], P[3], G[12];
    // rot: lane word-stride 9 (2-way bank alias = free); pos: stride 3.
    #pragma unroll
    for (int c = 0; c < 9; ++c) R[c] = rsl[lane * 9 + c];
    #pragma unroll
    for (int c = 0; c < 3; ++c) P[c] = psl[lane * 3 + c];
    // goal record: 48 B at word-stride 12 -> 3x ds_read_b128, conflict-free.
    const float4* g4 = (const float4*)(sg + (size_t)(h0 + (u32)lane) * 12);
    ((float4*)G)[0] = g4[0];
    ((float4*)G)[1] = g4[1];
    ((float4*)G)[2] = g4[2];

    float c0, c1, c2;
    pose_cost(R, P, G, G + 9, c0, c1, c2);

    const long long idx = (long long)g * GRP + lane;
    out[idx]         = c0;   // fire-and-forget; never waited on
    out[N + idx]     = c1;
    out[2 * N + idx] = c2;

    if (!has_next) break;
    first = false;
    cur ^= 1;
    g = gn;
    h0 += hstep; if (h0 >= uH) h0 -= uH;
  }
}

// Generic fallback: one pose per thread, direct global reads.
__global__ __launch_bounds__(BLOCK) void traj_cost_generic(
    const float* __restrict__ pos, const float* __restrict__ rot,
    const float* __restrict__ gpos, const float* __restrict__ grot,
    float* __restrict__ out, long long N, int H)
{
  const long long stride = (long long)gridDim.x * BLOCK;
  for (long long idx = (long long)blockIdx.x * BLOCK + threadIdx.x; idx < N;
       idx += stride) {
    const int h = (int)(idx % (long long)H);
    float R[9], P[3], G[12];
    #pragma unroll
    for (int c = 0; c < 9; ++c) R[c] = rot[idx * 9 + c];
    #pragma unroll
    for (int c = 0; c < 3; ++c) P[c] = pos[idx * 3 + c];
    #pragma unroll
    for (int c = 0; c < 9; ++c) G[c] = grot[(size_t)h * 9 + c];
    #pragma unroll
    for (int c = 0; c < 3; ++c) G[9 + c] = gpos[(size_t)h * 3 + c];
    float c0, c1, c2;
    pose_cost(R, P, G, G + 9, c0, c1, c2);
    out[idx]         = c0;
    out[N + idx]     = c1;
    out[2 * N + idx] = c2;
  }
}

extern "C" void kernel_launch(void* const* d_in, const int* in_sizes, int n_in,
                              void* d_out, int out_size, void* d_ws, size_t ws_size,
                              hipStream_t stream) {
  const float* pos  = (const float*)d_in[0];
  const float* rot  = (const float*)d_in[1];
  const float* gpos = (const float*)d_in[2];
  const float* grot = (const float*)d_in[3];
  float* out = (float*)d_out;

  const long long N = (long long)in_sizes[0] / 3;   // B*H poses
  const int H = in_sizes[2] / 3;

  const size_t smem = (size_t)(4 * WAVE_W + 12 * H) * sizeof(float);
  const bool fast = (N % GRP == 0) && (H % GRP == 0) && (H >= GRP) &&
                    smem <= 64 * 1024;

  if (fast) {
    const u32 groups = (u32)(N / GRP);
    u32 blocks = (groups + 3) / 4;
    if (blocks > 1024u) blocks = 1024u;   // 4 blocks/CU resident (36.9 KB LDS)
    traj_cost_wave<<<blocks, BLOCK, smem, stream>>>(pos, rot, gpos, grot,
                                                    out, N, H);
  } else {
    const long long nb = (N + BLOCK - 1) / BLOCK;
    const int blocks = (int)(nb < 2048 ? nb : 2048);
    traj_cost_generic<<<blocks, BLOCK, 0, stream>>>(pos, rot, gpos, grot,
                                                    out, N, H);
  }
}

// Round 7
// 141.199 us; speedup vs baseline: 1.1665x; 1.0060x over previous
//
#include <hip/hip_runtime.h>
#include <math.h>

#define BLOCK 256
#define GOAL_MAX 1024            // LDS goal table: 12*H words (H=256 -> 12 KB)

typedef unsigned int u32;

__device__ __forceinline__ void pose_cost(const float* __restrict__ R,
                                          const float* __restrict__ P,
                                          const float* __restrict__ G,
                                          const float* __restrict__ GP,
                                          float& cost, float& rotn, float& gd)
{
  // t[i] = -sum_j G[j,i]*GP[j] + sum_j R[j,i]*P[j]
  float t0 = 0.f, t1 = 0.f, t2 = 0.f;
  #pragma unroll
  for (int j = 0; j < 3; ++j) {
    t0 += R[j*3+0]*P[j] - G[j*3+0]*GP[j];
    t1 += R[j*3+1]*P[j] - G[j*3+1]*GP[j];
    t2 += R[j*3+2]*P[j] - G[j*3+2]*GP[j];
  }
  const float pos_err = t0*t0 + t1*t1 + t2*t2;
  gd = __builtin_amdgcn_sqrtf(pos_err);                    // arg >= 0

  // ee_R_g[i,j] = sum_k G[k,i]*R[k,j]; d = I - ee_R_g
  float rn[3];
  #pragma unroll
  for (int i = 0; i < 3; ++i) {
    float q = 0.f;
    #pragma unroll
    for (int j = 0; j < 3; ++j) {
      float m = G[0+i]*R[0+j] + G[3+i]*R[3+j] + G[6+i]*R[6+j];
      float d = (i == j ? 1.f : 0.f) - m;
      q += d*d;
    }
    rn[i] = __builtin_amdgcn_sqrtf(q);
  }
  const float ssum = rn[0] + rn[1] + rn[2];
  rotn = __builtin_amdgcn_sqrtf(rn[0]*rn[0] + rn[1]*rn[1] + rn[2]*rn[2]);
  // rot_err = ssum^2 hinged on gd <= 100; sqrt(ssum^2)==ssum (ssum>=0);
  // convergence thresholds are 0 -> no-op on non-negative values.
  cost = (gd <= 100.0f ? ssum : 0.f) + gd;
}

// Dumb-direct streaming: one pose per thread, 12 INDEPENDENT global loads
// (AoS, lane-stride 9/3 words -> each wave-instr covers a contiguous 2.3KB /
// 0.75KB window: fully L1-captured, zero refetch). Goals from a per-block LDS
// table. No barrier / no waitcnt asm in the loop: maximize the number of
// memory requests the scheduler can keep in flight (R5 showed 2.9 TB/s with
// high per-thread MLP; staged/piped versions all capped at ~1.6 TB/s).
__global__ __launch_bounds__(BLOCK) void traj_cost_direct(
    const float* __restrict__ pos,    // (N, 3)
    const float* __restrict__ rot,    // (N, 3, 3)
    const float* __restrict__ gpos,   // (H, 3)
    const float* __restrict__ grot,   // (H, 3, 3)
    float* __restrict__ out,          // cost[N] | rot_err_norm[N] | goal_dist[N]
    long long N, int H, int hstaged)
{
  extern __shared__ float sg[];       // 12*H words: record h = [9 rot | 3 pos]
  const int tid = threadIdx.x;
  const u32 uH = (u32)H;

  if (hstaged) {
    // coalesced enough (L2-hot 12KB); once per block
    for (u32 k = tid; k < 12u * uH; k += BLOCK) {
      const u32 r = k / 12u, c = k % 12u;
      sg[k] = (c < 9u) ? grot[r * 9u + c] : gpos[r * 3u + (c - 9u)];
    }
    __syncthreads();                  // the only barrier in the kernel
  }

  const long long stride = (long long)gridDim.x * BLOCK;
  for (long long idx = (long long)blockIdx.x * BLOCK + tid; idx < N;
       idx += stride) {
    const u32 h = (u32)(idx % (long long)H);   // compiler strength-reduces

    float R[9], P[3], G[12];
    const float* rp = rot + idx * 9;
    const float* pp = pos + idx * 3;
    // 12 independent loads; compiler issues all before first use and can
    // hoist next iteration's loads under this iteration's compute.
    #pragma unroll
    for (int c = 0; c < 9; ++c) R[c] = rp[c];
    #pragma unroll
    for (int c = 0; c < 3; ++c) P[c] = pp[c];

    if (hstaged) {
      // 48B record at word-stride 12: 3x ds_read_b128, banks covered 2x = free
      const float4* g4 = (const float4*)(sg + (size_t)h * 12u);
      ((float4*)G)[0] = g4[0];
      ((float4*)G)[1] = g4[1];
      ((float4*)G)[2] = g4[2];
    } else {
      #pragma unroll
      for (int c = 0; c < 9; ++c) G[c] = grot[(size_t)h * 9 + c];
      #pragma unroll
      for (int c = 0; c < 3; ++c) G[9 + c] = gpos[(size_t)h * 3 + c];
    }

    float c0, c1, c2;
    pose_cost(R, P, G, G + 9, c0, c1, c2);

    out[idx]         = c0;    // fire-and-forget coalesced dword stores
    out[N + idx]     = c1;
    out[2 * N + idx] = c2;
  }
}

extern "C" void kernel_launch(void* const* d_in, const int* in_sizes, int n_in,
                              void* d_out, int out_size, void* d_ws, size_t ws_size,
                              hipStream_t stream) {
  const float* pos  = (const float*)d_in[0];
  const float* rot  = (const float*)d_in[1];
  const float* gpos = (const float*)d_in[2];
  const float* grot = (const float*)d_in[3];
  float* out = (float*)d_out;

  const long long N = (long long)in_sizes[0] / 3;   // B*H poses
  const int H = in_sizes[2] / 3;

  const int hstaged = (H <= GOAL_MAX) ? 1 : 0;
  const size_t smem = hstaged ? (size_t)12 * H * sizeof(float) : 0;

  // 2048 blocks, grid-stride (~4 iters): 8 blocks/CU resident (12KB LDS,
  // low VGPR), enough queued waves to hide HBM latency; staging overhead
  // = 2048 * 12KB = 25MB of L2-hot reads.
  long long nb = (N + BLOCK - 1) / BLOCK;
  const int blocks = (int)(nb < 2048 ? nb : 2048);

  traj_cost_direct<<<blocks, BLOCK, smem, stream>>>(pos, rot, gpos, grot, out,
                                                    N, H, hstaged);
}